// Round 5
// baseline (4513.318 us; speedup 1.0000x reference)
//
#include <hip/hip_runtime.h>
#include <hip/hip_cooperative_groups.h>
#include <stdint.h>
#include <stddef.h>

namespace cg = cooperative_groups;

#define BB 64
#define LL 196
#define FF 2048
#define HH 512
#define VV 9488
#define TT 16
#define KXX 3072          // H + F + H (x' = [xt, att_res, h])
#define MM (BB * LL)      // 12544
#define MEGA_G 512        // 2 blocks/CU x 256 CU, guaranteed co-resident

typedef short short8 __attribute__((ext_vector_type(8)));
typedef short short4v __attribute__((ext_vector_type(4)));
typedef float f32x4 __attribute__((ext_vector_type(4)));
typedef unsigned short u16;

__device__ __forceinline__ u16 f2bf(float f) {
  uint32_t u = __builtin_bit_cast(uint32_t, f);
  u += 0x7FFFu + ((u >> 16) & 1u);   // RNE
  return (u16)(u >> 16);
}
__device__ __forceinline__ float bf2f(u16 s) {
  return __builtin_bit_cast(float, ((uint32_t)s) << 16);
}
__device__ __forceinline__ float fast_tanh(float x) {
  return 1.0f - 2.0f / (1.0f + __expf(2.0f * x));  // stable both tails
}
__device__ __forceinline__ float fast_sig(float x) {
  return 1.0f / (1.0f + __expf(-x));
}
__device__ __forceinline__ float wred_sum(float v) {
#pragma unroll
  for (int o = 32; o; o >>= 1) v += __shfl_xor(v, o, 64);
  return v;
}
__device__ __forceinline__ float wred_max(float v) {
#pragma unroll
  for (int o = 32; o; o >>= 1) v = fmaxf(v, __shfl_xor(v, o, 64));
  return v;
}

__device__ __forceinline__ f32x4 mfma16(short8 a, short8 b, f32x4 c) {
  return __builtin_amdgcn_mfma_f32_16x16x32_bf16(a, b, c, 0, 0, 0);
}
__device__ __forceinline__ short8 ldbf(const u16* p) {
  return *reinterpret_cast<const short8*>(p);
}
__device__ __forceinline__ short8 ldf32(const float* p) {
  float4 a = *reinterpret_cast<const float4*>(p);
  float4 b = *reinterpret_cast<const float4*>(p + 4);
  short8 r;
  r[0] = (short)f2bf(a.x); r[1] = (short)f2bf(a.y); r[2] = (short)f2bf(a.z); r[3] = (short)f2bf(a.w);
  r[4] = (short)f2bf(b.x); r[5] = (short)f2bf(b.y); r[6] = (short)f2bf(b.z); r[7] = (short)f2bf(b.w);
  return r;
}

// ---------------- setup kernels ----------------
__global__ __launch_bounds__(256) void k_cvt(const float* __restrict__ s, u16* __restrict__ d, int n4) {
  int i = blockIdx.x * 256 + threadIdx.x;
  if (i >= n4) return;
  float4 v = reinterpret_cast<const float4*>(s)[i];
  ushort4 o; o.x = f2bf(v.x); o.y = f2bf(v.y); o.z = f2bf(v.z); o.w = f2bf(v.w);
  reinterpret_cast<ushort4*>(d)[i] = o;
}

__global__ __launch_bounds__(256) void k_wc(const float* __restrict__ Wih, const float* __restrict__ Whh,
                                            u16* __restrict__ Wc) {
  int i = blockIdx.x * 256 + threadIdx.x;
  if (i >= 2048 * KXX / 4) return;
  int idx = i * 4;
  int n = idx / KXX, k = idx - n * KXX;
  const float* p = (k < 2560) ? (Wih + (size_t)n * 2560 + k) : (Whh + (size_t)n * HH + (k - 2560));
  float4 v = *reinterpret_cast<const float4*>(p);
  ushort4 o; o.x = f2bf(v.x); o.y = f2bf(v.y); o.z = f2bf(v.z); o.w = f2bf(v.w);
  reinterpret_cast<ushort4*>(Wc)[i] = o;
}

__global__ __launch_bounds__(256) void k_xemb(const float* __restrict__ emb, const int* __restrict__ seq,
                                              u16* __restrict__ X) {
  int i = blockIdx.x * 256 + threadIdx.x;
  if (i >= TT * BB * HH / 4) return;
  int idx = i * 4;
  int t = idx / (BB * HH);
  int r = idx - t * (BB * HH);
  int b = r / HH, k = r - b * HH;
  int tok = seq[b * 17 + t];
  float4 v = *reinterpret_cast<const float4*>(emb + (size_t)tok * HH + k);
  ushort4 o; o.x = f2bf(v.x); o.y = f2bf(v.y); o.z = f2bf(v.z); o.w = f2bf(v.w);
  reinterpret_cast<ushort4*>(X)[i] = o;
}

// h0 = c0 = fc @ lin_W^T + lin_b
__global__ __launch_bounds__(256) void k_h0(const u16* __restrict__ fcb, const u16* __restrict__ linWb,
                                            const float* __restrict__ lin_b,
                                            u16* __restrict__ hb, float* __restrict__ c) {
  int lane = threadIdx.x & 63;
  int m0 = (threadIdx.x >> 6) * 16, n0 = blockIdx.x * 16;
  const u16* xr = fcb + (size_t)(m0 + (lane & 15)) * FF + ((lane >> 4) * 8);
  const u16* wr = linWb + (size_t)(n0 + (lane & 15)) * FF + ((lane >> 4) * 8);
  f32x4 acc = {0.f, 0.f, 0.f, 0.f};
#pragma unroll 8
  for (int kk = 0; kk < 64; ++kk)
    acc = mfma16(ldbf(xr + kk * 32), ldbf(wr + kk * 32), acc);
  int col = n0 + (lane & 15);
  float bias = lin_b[col];
#pragma unroll
  for (int j = 0; j < 4; ++j) {
    int row = m0 + (lane >> 4) * 4 + j;
    float v = acc[j] + bias;
    hb[row * HH + col] = f2bf(v);
    c[row * HH + col] = v;
  }
}

// p_att = att_feats @ ctx_W^T + ctx_b. 128x128 tile; 64B LDS rows (analysis:
// frag reads perfectly bank-balanced, staging writes 2-way=free); XCD remap.
__global__ __launch_bounds__(256) void k_patt(const u16* __restrict__ attb,
                                              const u16* __restrict__ ctxWb, const float* __restrict__ ctx_b,
                                              u16* __restrict__ p_att) {
  __shared__ __align__(16) u16 As[128][32];
  __shared__ __align__(16) u16 Bs[128][32];
  int d = blockIdx.x;
  int bid = (d & 7) * 49 + (d >> 3);     // 392 = 8*49, bijective XCD remap
  int mb = bid >> 2, nb = bid & 3;       // 98 x 4
  int m0 = mb * 128, n0 = nb * 128;
  int tid = threadIdx.x;
  int wid = tid >> 6, lane = tid & 63;
  int wr = wid >> 1, wc = wid & 1;       // wave quadrant (64x64)
  int ar = lane & 15, ak = (lane >> 4) * 8;
  int rt = tid >> 1, st = tid & 1;       // staging: row, 16-elem segment
  const u16* agp = attb + (size_t)(m0 + rt) * FF + st * 16;
  const u16* bgp = ctxWb + (size_t)(n0 + rt) * FF + st * 16;

  f32x4 zero = {0.f, 0.f, 0.f, 0.f};
  f32x4 acc[4][4];
#pragma unroll
  for (int i = 0; i < 4; ++i)
#pragma unroll
    for (int j = 0; j < 4; ++j) acc[i][j] = zero;

  for (int ks = 0; ks < 64; ++ks) {
    int k0 = ks * 32;
    short8 a0 = ldbf(agp + k0);
    short8 a1 = ldbf(agp + k0 + 8);
    short8 b0 = ldbf(bgp + k0);
    short8 b1 = ldbf(bgp + k0 + 8);
    __syncthreads();
    *reinterpret_cast<short8*>(&As[rt][st * 16]) = a0;
    *reinterpret_cast<short8*>(&As[rt][st * 16 + 8]) = a1;
    *reinterpret_cast<short8*>(&Bs[rt][st * 16]) = b0;
    *reinterpret_cast<short8*>(&Bs[rt][st * 16 + 8]) = b1;
    __syncthreads();
    short8 af[4], bfr[4];
#pragma unroll
    for (int i = 0; i < 4; ++i)
      af[i] = *reinterpret_cast<const short8*>(&As[wr * 64 + i * 16 + ar][ak]);
#pragma unroll
    for (int j = 0; j < 4; ++j)
      bfr[j] = *reinterpret_cast<const short8*>(&Bs[wc * 64 + j * 16 + ar][ak]);
#pragma unroll
    for (int i = 0; i < 4; ++i)
#pragma unroll
      for (int j = 0; j < 4; ++j)
        acc[i][j] = mfma16(af[i], bfr[j], acc[i][j]);
  }
#pragma unroll
  for (int j = 0; j < 4; ++j) {
    int col = n0 + wc * 64 + j * 16 + ar;
    float bias = ctx_b[col];
#pragma unroll
    for (int i = 0; i < 4; ++i)
#pragma unroll
      for (int q = 0; q < 4; ++q) {
        int row = m0 + wr * 64 + i * 16 + (lane >> 4) * 4 + q;
        p_att[(size_t)row * HH + col] = f2bf(acc[i][j][q] + bias);
      }
  }
}

// ---------------- per-step device bodies ----------------
__device__ __forceinline__ void dev_atth(int nt, const u16* __restrict__ hb, const u16* __restrict__ h2aWb,
                                         const float* __restrict__ h2ab, float* __restrict__ ah) {
  int lane = threadIdx.x & 63;
  int m0 = (threadIdx.x >> 6) * 16, n0 = nt * 16;
  int ak = (lane >> 4) * 8;
  const u16* xr = hb + (size_t)(m0 + (lane & 15)) * HH + ak;
  const u16* wr = h2aWb + (size_t)(n0 + (lane & 15)) * HH + ak;
  f32x4 acc = {0.f, 0.f, 0.f, 0.f};
#pragma unroll
  for (int kk = 0; kk < 16; ++kk)
    acc = mfma16(ldbf(xr + kk * 32), ldbf(wr + kk * 32), acc);
  int col = n0 + (lane & 15);
  float bias = h2ab[col];
#pragma unroll
  for (int j = 0; j < 4; ++j)
    ah[(size_t)(m0 + (lane >> 4) * 4 + j) * HH + col] = acc[j] + bias;
}

__device__ __forceinline__ void dev_e(int bid4, const u16* __restrict__ p_att, const float* __restrict__ ah,
                                      const float* __restrict__ alphaW, const float* __restrict__ alphab,
                                      float* __restrict__ e) {
  int gw = bid4 * 4 + (threadIdx.x >> 6);   // [0, 12544)
  int lane = threadIdx.x & 63;
  int b = gw / LL, l = gw - b * LL;
  short8 pa = ldbf(p_att + (size_t)gw * HH + lane * 8);
  const float4* ap = reinterpret_cast<const float4*>(ah + (size_t)b * HH + lane * 8);
  float4 a0 = ap[0], a1 = ap[1];
  const float4* wp = reinterpret_cast<const float4*>(alphaW + lane * 8);
  float4 w0 = wp[0], w1 = wp[1];
  float s = fast_tanh(bf2f((u16)pa[0]) + a0.x) * w0.x
          + fast_tanh(bf2f((u16)pa[1]) + a0.y) * w0.y
          + fast_tanh(bf2f((u16)pa[2]) + a0.z) * w0.z
          + fast_tanh(bf2f((u16)pa[3]) + a0.w) * w0.w
          + fast_tanh(bf2f((u16)pa[4]) + a1.x) * w1.x
          + fast_tanh(bf2f((u16)pa[5]) + a1.y) * w1.y
          + fast_tanh(bf2f((u16)pa[6]) + a1.z) * w1.z
          + fast_tanh(bf2f((u16)pa[7]) + a1.w) * w1.w;
  s = wred_sum(s);
  if (!lane) e[b * 256 + l] = s + alphab[0];
}

template<bool LWB>
__device__ __forceinline__ void dev_logits(int nt, const u16* __restrict__ hb, const u16* __restrict__ lWb,
                                           const float* __restrict__ lW, const float* __restrict__ lb,
                                           float* __restrict__ logits) {
  int lane = threadIdx.x & 63;
  int m0 = (threadIdx.x >> 6) * 16, n0 = nt * 16;
  int ak = (lane >> 4) * 8;
  const u16* xr = hb + (size_t)(m0 + (lane & 15)) * HH + ak;
  int wn = n0 + (lane & 15);
  f32x4 acc = {0.f, 0.f, 0.f, 0.f};
#pragma unroll
  for (int kk = 0; kk < 16; ++kk) {
    short8 a = ldbf(xr + kk * 32);
    short8 bv;
    if (LWB) bv = ldbf(lWb + (size_t)wn * HH + ak + kk * 32);
    else     bv = ldf32(lW + (size_t)wn * HH + ak + kk * 32);
    acc = mfma16(a, bv, acc);
  }
  int col = n0 + (lane & 15);
  float bias = lb[col];
#pragma unroll
  for (int j = 0; j < 4; ++j)
    logits[(size_t)(m0 + (lane >> 4) * 4 + j) * VV + col] = acc[j] + bias;
}

__device__ __forceinline__ void dev_lsm(float* red, int b, const float* __restrict__ logits,
                                        float* __restrict__ out, int tstep) {
  const float4* row4 = reinterpret_cast<const float4*>(logits + (size_t)b * VV);
  int t = threadIdx.x, wid = t >> 6, lane = t & 63;
  float4 v[10];
  float m = -1e30f;
#pragma unroll
  for (int p = 0; p < 10; ++p) {
    int i4 = p * 256 + t;
    if (i4 < VV / 4) {
      v[p] = row4[i4];
      m = fmaxf(m, fmaxf(fmaxf(v[p].x, v[p].y), fmaxf(v[p].z, v[p].w)));
    } else {
      v[p] = make_float4(-1e30f, -1e30f, -1e30f, -1e30f);
    }
  }
  m = wred_max(m);
  if (!lane) red[wid] = m;
  __syncthreads();
  m = fmaxf(fmaxf(red[0], red[1]), fmaxf(red[2], red[3]));
  float s = 0.f;
#pragma unroll
  for (int p = 0; p < 10; ++p)
    s += __expf(v[p].x - m) + __expf(v[p].y - m) + __expf(v[p].z - m) + __expf(v[p].w - m);
  s = wred_sum(s);
  if (!lane) red[4 + wid] = s;
  __syncthreads();
  s = red[4] + red[5] + red[6] + red[7];
  float lse = m + __logf(s);
  float4* orow = reinterpret_cast<float4*>(out + ((size_t)b * TT + tstep) * VV);
#pragma unroll
  for (int p = 0; p < 10; ++p) {
    int i4 = p * 256 + t;
    if (i4 < VV / 4)
      orow[i4] = make_float4(v[p].x - lse, v[p].y - lse, v[p].z - lse, v[p].w - lse);
  }
}

// attR: 512 works = b(64) x f-chunk(8) of 256 feats
struct SMattR { float w_s[LL]; float red[8]; float part[4][256]; };
__device__ __forceinline__ void dev_attR2(char* smraw, int w, const float* __restrict__ e,
                                          const u16* __restrict__ attb, u16* __restrict__ xatt) {
  SMattR& s = *reinterpret_cast<SMattR*>(smraw);
  int b = w >> 3, f8 = w & 7;
  int t = threadIdx.x, wid = t >> 6, lane = t & 63;
  float ev = (t < LL) ? e[b * 256 + t] : -1e30f;
  float m = wred_max(ev);
  if (!lane) s.red[wid] = m;
  __syncthreads();
  m = fmaxf(fmaxf(s.red[0], s.red[1]), fmaxf(s.red[2], s.red[3]));
  float ex = __expf(ev - m);
  float sum = wred_sum(ex);
  if (!lane) s.red[4 + wid] = sum;
  __syncthreads();
  sum = s.red[4] + s.red[5] + s.red[6] + s.red[7];
  if (t < LL) s.w_s[t] = ex / sum;
  __syncthreads();

  int f0 = f8 * 256 + lane * 4;
  float a0 = 0.f, a1 = 0.f, a2 = 0.f, a3 = 0.f;
  int l0 = wid * 49;
  const u16* ap = attb + ((size_t)(b * LL + l0)) * FF + f0;
#pragma unroll 7
  for (int l = 0; l < 49; ++l) {
    float wv = s.w_s[l0 + l];
    short4v av = *reinterpret_cast<const short4v*>(ap);
    ap += FF;
    a0 += wv * bf2f((u16)av[0]); a1 += wv * bf2f((u16)av[1]);
    a2 += wv * bf2f((u16)av[2]); a3 += wv * bf2f((u16)av[3]);
  }
  *reinterpret_cast<float4*>(&s.part[wid][lane * 4]) = make_float4(a0, a1, a2, a3);
  __syncthreads();
  float v = s.part[0][t] + s.part[1][t] + s.part[2][t] + s.part[3][t];
  xatt[(size_t)b * FF + f8 * 256 + t] = f2bf(v);
}

// gates+LSTM: 128 works = jt(32) x mq(4); 4 waves = K-quarters
struct SMgl { float sm[4][4][16][16]; };
__device__ __forceinline__ void dev_gatelstm(char* smraw, int work,
                                             const u16* __restrict__ Xemb, const u16* __restrict__ xatt,
                                             const u16* __restrict__ hb_in, const u16* __restrict__ Wc,
                                             float* __restrict__ c, u16* __restrict__ hb_out, int tstep) {
  SMgl& s = *reinterpret_cast<SMgl*>(smraw);
  int jt = work >> 2, mq = work & 3;
  int m0 = mq * 16;
  int lane = threadIdx.x & 63, kq = threadIdx.x >> 6;
  int ar = lane & 15, ak8 = (lane >> 4) * 8;
  int m = m0 + ar;
  int wn = jt * 16 + ar;
  f32x4 zero = {0.f, 0.f, 0.f, 0.f};
  f32x4 acc[4] = {zero, zero, zero, zero};
  const u16* xr0 = Xemb + ((size_t)tstep * BB + m) * HH;
  const u16* xr1 = xatt + (size_t)m * FF;
  const u16* xr2 = hb_in + (size_t)m * HH;

#pragma unroll 4
  for (int kk = 0; kk < 24; ++kk) {
    int k = kq * 768 + kk * 32 + ak8;
    short8 a;
    if (k < 512)       a = ldbf(xr0 + k);
    else if (k < 2560) a = ldbf(xr1 + (k - 512));
    else               a = ldbf(xr2 + (k - 2560));
    short8 bv[4];
#pragma unroll
    for (int g = 0; g < 4; ++g)
      bv[g] = ldbf(Wc + (size_t)(g * 512 + wn) * KXX + k);
#pragma unroll
    for (int g = 0; g < 4; ++g) acc[g] = mfma16(a, bv[g], acc[g]);
  }
#pragma unroll
  for (int g = 0; g < 4; ++g)
#pragma unroll
    for (int q = 0; q < 4; ++q)
      s.sm[kq][g][(lane >> 4) * 4 + q][ar] = acc[g][q];
  __syncthreads();
  int r = threadIdx.x >> 4, cc = threadIdx.x & 15;
  float gi = s.sm[0][0][r][cc] + s.sm[1][0][r][cc] + s.sm[2][0][r][cc] + s.sm[3][0][r][cc];
  float gf = s.sm[0][1][r][cc] + s.sm[1][1][r][cc] + s.sm[2][1][r][cc] + s.sm[3][1][r][cc];
  float gg = s.sm[0][2][r][cc] + s.sm[1][2][r][cc] + s.sm[2][2][r][cc] + s.sm[3][2][r][cc];
  float go = s.sm[0][3][r][cc] + s.sm[1][3][r][cc] + s.sm[2][3][r][cc] + s.sm[3][3][r][cc];
  int idx = (m0 + r) * HH + jt * 16 + cc;
  float cn = fast_sig(gf) * c[idx] + fast_sig(gi) * fast_tanh(gg);
  float hn = fast_sig(go) * fast_tanh(cn);
  c[idx] = cn;
  hb_out[idx] = f2bf(hn);
}

// ---------------- mega cooperative kernel ----------------
struct MegaArgs {
  const u16 *p_att, *attb, *Wc, *lWb, *h2aWb, *Xemb;
  const float *lb, *h2ab, *alphaW, *alphab;
  float *c;
  u16 *hbA, *hbB, *xatt;
  float *eb, *ah, *logits, *out;
};

__global__ __launch_bounds__(256, 2) void k_mega(MegaArgs a) {
  cg::grid_group grid = cg::this_grid();
  __shared__ __align__(16) char smraw[sizeof(SMgl)];   // 16 KB, reused per phase
  int bid = blockIdx.x;

  for (int t = -1; t < TT; ++t) {
    const u16* hbi = (t & 1) ? a.hbB : a.hbA;   // hb_in(t);  t=-1 -> unused
    u16* hbo = (t & 1) ? a.hbA : a.hbB;         // hb_out(t); t=-1 -> hbA (h0)
    if (t >= 0) {
      // phase A: softmax + attention-weighted sum -> xatt (512 works, 1:1)
      dev_attR2(smraw, bid, a.eb, a.attb, a.xatt);
      grid.sync();
      // phase B: gates + LSTM (128 works)
      if (bid < 128) dev_gatelstm(smraw, bid, a.Xemb, a.xatt, hbi, a.Wc, a.c, hbo, t);
      grid.sync();
    }
    // phase C: logits(t) [593] + atth(t+1) [32]
    {
      int nlog = (t >= 0) ? 593 : 0;
      int ntot = nlog + ((t < TT - 1) ? 32 : 0);
      for (int w = bid; w < ntot; w += MEGA_G) {
        if (w < nlog) dev_logits<true>(w, hbo, a.lWb, nullptr, a.lb, a.logits);
        else dev_atth(w - nlog, hbo, a.h2aWb, a.h2ab, a.ah);
      }
    }
    grid.sync();
    // phase D: lsm(t) [64] + e(t+1) [3136]
    {
      int nl = (t >= 0) ? 64 : 0;
      int ntot = nl + ((t < TT - 1) ? (MM / 4) : 0);
      for (int w = bid; w < ntot; w += MEGA_G) {
        if (w < nl) dev_lsm(reinterpret_cast<float*>(smraw), w, a.logits, a.out, t);
        else dev_e(w - nl, a.p_att, a.ah, a.alphaW, a.alphab, a.eb);
      }
    }
    grid.sync();
  }
}

// ---------------- fallback per-step kernels (R3-validated path) ----------------
__global__ __launch_bounds__(256) void k_atth(const u16* __restrict__ hb, const u16* __restrict__ h2aWb,
                                              const float* __restrict__ h2ab, float* __restrict__ ah) {
  dev_atth(blockIdx.x, hb, h2aWb, h2ab, ah);
}
__global__ __launch_bounds__(256) void k_e(const u16* __restrict__ p_att, const float* __restrict__ ah,
                                           const float* __restrict__ alphaW, const float* __restrict__ alphab,
                                           float* __restrict__ e) {
  dev_e(blockIdx.x, p_att, ah, alphaW, alphab, e);
}
__global__ __launch_bounds__(256) void k_attR(const float* __restrict__ e, const u16* __restrict__ attb,
                                              u16* __restrict__ xatt) {
  __shared__ __align__(16) char smraw[sizeof(SMattR)];
  dev_attR2(smraw, blockIdx.x, e, attb, xatt);
}
__global__ __launch_bounds__(256) void k_gatelstm(const u16* __restrict__ Xemb, const u16* __restrict__ xatt,
                                                  const u16* __restrict__ hb_in, const u16* __restrict__ Wc,
                                                  float* __restrict__ c, u16* __restrict__ hb_out, int tstep) {
  __shared__ __align__(16) char smraw[sizeof(SMgl)];
  dev_gatelstm(smraw, blockIdx.x, Xemb, xatt, hb_in, Wc, c, hb_out, tstep);
}
__global__ __launch_bounds__(256) void k_logatt(const u16* __restrict__ hb, const u16* __restrict__ lWb,
                                                const float* __restrict__ lb, float* __restrict__ logits,
                                                const u16* __restrict__ h2aWb, const float* __restrict__ h2ab,
                                                float* __restrict__ ah, int do_next) {
  int bid = blockIdx.x;
  if (bid < 593) dev_logits<true>(bid, hb, lWb, nullptr, lb, logits);
  else if (do_next) dev_atth(bid - 593, hb, h2aWb, h2ab, ah);
}
__global__ __launch_bounds__(256) void k_lsme(const float* __restrict__ logits, float* __restrict__ out,
                                              int tstep, const u16* __restrict__ p_att,
                                              const float* __restrict__ ah, const float* __restrict__ alphaW,
                                              const float* __restrict__ alphab, float* __restrict__ e,
                                              int do_next) {
  __shared__ float red[8];
  int bid = blockIdx.x;
  if (bid < 64) dev_lsm(red, bid, logits, out, tstep);
  else if (do_next) dev_e(bid - 64, p_att, ah, alphaW, alphab, e);
}

// ---------------- host ----------------
extern "C" void kernel_launch(void* const* d_in, const int* in_sizes, int n_in,
                              void* d_out, int out_size, void* d_ws, size_t ws_size,
                              hipStream_t stream) {
  const float* fc      = (const float*)d_in[0];
  const float* attf    = (const float*)d_in[1];
  const int*   seq     = (const int*)d_in[2];
  const float* lin_W   = (const float*)d_in[3];
  const float* lin_b   = (const float*)d_in[4];
  const float* emb     = (const float*)d_in[5];
  const float* Wih     = (const float*)d_in[6];
  const float* Whh     = (const float*)d_in[7];
  const float* ctx_W   = (const float*)d_in[8];
  const float* ctx_b   = (const float*)d_in[9];
  const float* h2a_W   = (const float*)d_in[10];
  const float* h2a_b   = (const float*)d_in[11];
  const float* alpha_W = (const float*)d_in[12];
  const float* alpha_b = (const float*)d_in[13];
  const float* logit_W = (const float*)d_in[14];
  const float* logit_b = (const float*)d_in[15];
  float* out = (float*)d_out;

  char* base = (char*)d_ws;
  size_t off = 0;
  auto alloc = [&](size_t bytes) -> char* {
    off = (off + 255) & ~(size_t)255;
    char* p = base + off;
    off += bytes;
    return p;
  };
  u16*   p_att  = (u16*)alloc((size_t)MM * HH * 2);
  u16*   ctxWb  = (u16*)alloc((size_t)HH * FF * 2);
  u16*   linWb  = (u16*)alloc((size_t)HH * FF * 2);
  u16*   fcb    = (u16*)alloc((size_t)BB * FF * 2);
  u16*   h2aWb  = (u16*)alloc((size_t)HH * HH * 2);
  u16*   Xemb   = (u16*)alloc((size_t)TT * BB * HH * 2);
  float* c      = (float*)alloc((size_t)BB * HH * 4);
  u16*   hbA    = (u16*)alloc((size_t)BB * HH * 2);
  u16*   hbB    = (u16*)alloc((size_t)BB * HH * 2);
  u16*   xatt   = (u16*)alloc((size_t)BB * FF * 2);
  float* eb     = (float*)alloc((size_t)BB * 256 * 4);
  float* ah     = (float*)alloc((size_t)BB * HH * 4);
  float* logits = (float*)alloc((size_t)BB * VV * 4);
  u16*   Wc     = (u16*)alloc((size_t)2048 * KXX * 2);
  u16*   lWb    = (u16*)alloc((size_t)VV * HH * 2);
  u16*   attb   = (u16*)alloc((size_t)MM * FF * 2);
  bool fits = off <= ws_size;   // ~110 MB total; ws is expected to cover this

  k_cvt<<<(HH * FF / 4 + 255) / 256, 256, 0, stream>>>(ctx_W, ctxWb, HH * FF / 4);
  k_cvt<<<(HH * FF / 4 + 255) / 256, 256, 0, stream>>>(lin_W, linWb, HH * FF / 4);
  k_cvt<<<(BB * FF / 4 + 255) / 256, 256, 0, stream>>>(fc, fcb, BB * FF / 4);
  k_cvt<<<(HH * HH / 4 + 255) / 256, 256, 0, stream>>>(h2a_W, h2aWb, HH * HH / 4);
  k_cvt<<<(VV * HH / 4 + 255) / 256, 256, 0, stream>>>(logit_W, lWb, VV * HH / 4);
  k_wc<<<(2048 * KXX / 4 + 255) / 256, 256, 0, stream>>>(Wih, Whh, Wc);
  k_cvt<<<(MM * FF / 4 + 255) / 256, 256, 0, stream>>>(attf, attb, MM * FF / 4);
  k_xemb<<<(TT * BB * HH / 4 + 255) / 256, 256, 0, stream>>>(emb, seq, Xemb);
  k_h0<<<32, 256, 0, stream>>>(fcb, linWb, lin_b, hbA, c);
  k_patt<<<392, 256, 0, stream>>>(attb, ctxWb, ctx_b, p_att);

  MegaArgs ma;
  ma.p_att = p_att; ma.attb = attb; ma.Wc = Wc; ma.lWb = lWb;
  ma.h2aWb = h2aWb; ma.Xemb = Xemb;
  ma.lb = logit_b; ma.h2ab = h2a_b; ma.alphaW = alpha_W; ma.alphab = alpha_b;
  ma.c = c; ma.hbA = hbA; ma.hbB = hbB; ma.xatt = xatt;
  ma.eb = eb; ma.ah = ah; ma.logits = logits; ma.out = out;
  void* kargs[] = { (void*)&ma };
  hipError_t rc = hipErrorUnknown;
  if (fits)
    rc = hipLaunchCooperativeKernel((const void*)k_mega, dim3(MEGA_G), dim3(256), kargs, 0, stream);

  if (rc != hipSuccess) {
    // fallback: proven multi-kernel path (same device bodies)
    k_atth<<<32, 256, 0, stream>>>(hbA, h2aWb, h2a_b, ah);
    k_e<<<MM / 4, 256, 0, stream>>>(p_att, ah, alpha_W, alpha_b, eb);
    for (int t = 0; t < TT; ++t) {
      u16* hb_in  = (t & 1) ? hbB : hbA;
      u16* hb_out = (t & 1) ? hbA : hbB;
      int more = (t < TT - 1) ? 1 : 0;
      k_attR<<<512, 256, 0, stream>>>(eb, attb, xatt);
      k_gatelstm<<<128, 256, 0, stream>>>(Xemb, xatt, hb_in, Wc, c, hb_out, t);
      k_logatt<<<625, 256, 0, stream>>>(hb_out, lWb, logit_b, logits, h2aWb, h2a_b, ah, more);
      k_lsme<<<64 + MM / 4, 256, 0, stream>>>(logits, out, t, p_att, ah, alpha_W, alpha_b, eb, more);
    }
  }
}

// Round 6
// 894.808 us; speedup vs baseline: 5.0439x; 5.0439x over previous
//
#include <hip/hip_runtime.h>
#include <stdint.h>
#include <stddef.h>

#define BB 64
#define LL 196
#define FF 2048
#define HH 512
#define VV 9488
#define TT 16
#define KXX 3072          // H + F + H (x' = [xt, att_res, h])
#define MM (BB * LL)      // 12544

typedef short short8 __attribute__((ext_vector_type(8)));
typedef short short4v __attribute__((ext_vector_type(4)));
typedef float f32x4 __attribute__((ext_vector_type(4)));
typedef unsigned short u16;

__device__ __forceinline__ u16 f2bf(float f) {
  uint32_t u = __builtin_bit_cast(uint32_t, f);
  u += 0x7FFFu + ((u >> 16) & 1u);   // RNE
  return (u16)(u >> 16);
}
__device__ __forceinline__ float bf2f(u16 s) {
  return __builtin_bit_cast(float, ((uint32_t)s) << 16);
}
__device__ __forceinline__ float fast_tanh(float x) {
  return 1.0f - 2.0f / (1.0f + __expf(2.0f * x));  // stable both tails
}
__device__ __forceinline__ float fast_sig(float x) {
  return 1.0f / (1.0f + __expf(-x));
}
__device__ __forceinline__ float wred_sum(float v) {
#pragma unroll
  for (int o = 32; o; o >>= 1) v += __shfl_xor(v, o, 64);
  return v;
}
__device__ __forceinline__ float wred_max(float v) {
#pragma unroll
  for (int o = 32; o; o >>= 1) v = fmaxf(v, __shfl_xor(v, o, 64));
  return v;
}

__device__ __forceinline__ f32x4 mfma16(short8 a, short8 b, f32x4 c) {
  return __builtin_amdgcn_mfma_f32_16x16x32_bf16(a, b, c, 0, 0, 0);
}
__device__ __forceinline__ short8 ldbf(const u16* p) {
  return *reinterpret_cast<const short8*>(p);
}

// ---------------- setup kernels ----------------
__global__ __launch_bounds__(256) void k_cvt(const float* __restrict__ s, u16* __restrict__ d, int n4) {
  int i = blockIdx.x * 256 + threadIdx.x;
  if (i >= n4) return;
  float4 v = reinterpret_cast<const float4*>(s)[i];
  ushort4 o; o.x = f2bf(v.x); o.y = f2bf(v.y); o.z = f2bf(v.z); o.w = f2bf(v.w);
  reinterpret_cast<ushort4*>(d)[i] = o;
}

// 4 weight conversions in one launch. Ranges are exact multiples of 256:
// ctx 1024 blk | lin 1024 | h2a 256 | logit 4744  => 7048 blocks total.
__global__ __launch_bounds__(256) void k_cvtall(const float* __restrict__ s0, u16* __restrict__ d0,
                                                const float* __restrict__ s1, u16* __restrict__ d1,
                                                const float* __restrict__ s2, u16* __restrict__ d2,
                                                const float* __restrict__ s3, u16* __restrict__ d3) {
  int blk = blockIdx.x;
  const float* s; u16* d; int rel;
  if (blk < 1024)      { s = s0; d = d0; rel = blk; }
  else if (blk < 2048) { s = s1; d = d1; rel = blk - 1024; }
  else if (blk < 2304) { s = s2; d = d2; rel = blk - 2048; }
  else                 { s = s3; d = d3; rel = blk - 2304; }
  int i = rel * 256 + threadIdx.x;
  float4 v = reinterpret_cast<const float4*>(s)[i];
  ushort4 o; o.x = f2bf(v.x); o.y = f2bf(v.y); o.z = f2bf(v.z); o.w = f2bf(v.w);
  reinterpret_cast<ushort4*>(d)[i] = o;
}

__global__ __launch_bounds__(256) void k_wc(const float* __restrict__ Wih, const float* __restrict__ Whh,
                                            u16* __restrict__ Wc) {
  int i = blockIdx.x * 256 + threadIdx.x;
  if (i >= 2048 * KXX / 4) return;
  int idx = i * 4;
  int n = idx / KXX, k = idx - n * KXX;
  const float* p = (k < 2560) ? (Wih + (size_t)n * 2560 + k) : (Whh + (size_t)n * HH + (k - 2560));
  float4 v = *reinterpret_cast<const float4*>(p);
  ushort4 o; o.x = f2bf(v.x); o.y = f2bf(v.y); o.z = f2bf(v.z); o.w = f2bf(v.w);
  reinterpret_cast<ushort4*>(Wc)[i] = o;
}

__global__ __launch_bounds__(256) void k_xemb(const float* __restrict__ emb, const int* __restrict__ seq,
                                              u16* __restrict__ X) {
  int i = blockIdx.x * 256 + threadIdx.x;
  if (i >= TT * BB * HH / 4) return;
  int idx = i * 4;
  int t = idx / (BB * HH);
  int r = idx - t * (BB * HH);
  int b = r / HH, k = r - b * HH;
  int tok = seq[b * 17 + t];
  float4 v = *reinterpret_cast<const float4*>(emb + (size_t)tok * HH + k);
  ushort4 o; o.x = f2bf(v.x); o.y = f2bf(v.y); o.z = f2bf(v.z); o.w = f2bf(v.w);
  reinterpret_cast<ushort4*>(X)[i] = o;
}

// h0 = c0 = fc @ lin_W^T + lin_b
__global__ __launch_bounds__(256) void k_h0(const u16* __restrict__ fcb, const u16* __restrict__ linWb,
                                            const float* __restrict__ lin_b,
                                            u16* __restrict__ hb, float* __restrict__ c) {
  int lane = threadIdx.x & 63;
  int m0 = (threadIdx.x >> 6) * 16, n0 = blockIdx.x * 16;
  const u16* xr = fcb + (size_t)(m0 + (lane & 15)) * FF + ((lane >> 4) * 8);
  const u16* wr = linWb + (size_t)(n0 + (lane & 15)) * FF + ((lane >> 4) * 8);
  f32x4 acc = {0.f, 0.f, 0.f, 0.f};
#pragma unroll 8
  for (int kk = 0; kk < 64; ++kk)
    acc = mfma16(ldbf(xr + kk * 32), ldbf(wr + kk * 32), acc);
  int col = n0 + (lane & 15);
  float bias = lin_b[col];
#pragma unroll
  for (int j = 0; j < 4; ++j) {
    int row = m0 + (lane >> 4) * 4 + j;
    float v = acc[j] + bias;
    hb[row * HH + col] = f2bf(v);
    c[row * HH + col] = v;
  }
}

// p_att = att_feats @ ctx_W^T + ctx_b. 128x128 tile; 64B LDS rows (analysis:
// frag reads bank-balanced, staging writes 2-way=free); bijective XCD remap.
__global__ __launch_bounds__(256) void k_patt(const u16* __restrict__ attb,
                                              const u16* __restrict__ ctxWb, const float* __restrict__ ctx_b,
                                              u16* __restrict__ p_att) {
  __shared__ __align__(16) u16 As[128][32];
  __shared__ __align__(16) u16 Bs[128][32];
  int d = blockIdx.x;
  int bid = (d & 7) * 49 + (d >> 3);     // 392 = 8*49, bijective XCD remap
  int mb = bid >> 2, nb = bid & 3;       // 98 x 4
  int m0 = mb * 128, n0 = nb * 128;
  int tid = threadIdx.x;
  int wid = tid >> 6, lane = tid & 63;
  int wr = wid >> 1, wc = wid & 1;       // wave quadrant (64x64)
  int ar = lane & 15, ak = (lane >> 4) * 8;
  int rt = tid >> 1, st = tid & 1;       // staging: row, 16-elem segment
  const u16* agp = attb + (size_t)(m0 + rt) * FF + st * 16;
  const u16* bgp = ctxWb + (size_t)(n0 + rt) * FF + st * 16;

  f32x4 zero = {0.f, 0.f, 0.f, 0.f};
  f32x4 acc[4][4];
#pragma unroll
  for (int i = 0; i < 4; ++i)
#pragma unroll
    for (int j = 0; j < 4; ++j) acc[i][j] = zero;

  for (int ks = 0; ks < 64; ++ks) {
    int k0 = ks * 32;
    short8 a0 = ldbf(agp + k0);
    short8 a1 = ldbf(agp + k0 + 8);
    short8 b0 = ldbf(bgp + k0);
    short8 b1 = ldbf(bgp + k0 + 8);
    __syncthreads();
    *reinterpret_cast<short8*>(&As[rt][st * 16]) = a0;
    *reinterpret_cast<short8*>(&As[rt][st * 16 + 8]) = a1;
    *reinterpret_cast<short8*>(&Bs[rt][st * 16]) = b0;
    *reinterpret_cast<short8*>(&Bs[rt][st * 16 + 8]) = b1;
    __syncthreads();
    short8 af[4], bfr[4];
#pragma unroll
    for (int i = 0; i < 4; ++i)
      af[i] = *reinterpret_cast<const short8*>(&As[wr * 64 + i * 16 + ar][ak]);
#pragma unroll
    for (int j = 0; j < 4; ++j)
      bfr[j] = *reinterpret_cast<const short8*>(&Bs[wc * 64 + j * 16 + ar][ak]);
#pragma unroll
    for (int i = 0; i < 4; ++i)
#pragma unroll
      for (int j = 0; j < 4; ++j)
        acc[i][j] = mfma16(af[i], bfr[j], acc[i][j]);
  }
#pragma unroll
  for (int j = 0; j < 4; ++j) {
    int col = n0 + wc * 64 + j * 16 + ar;
    float bias = ctx_b[col];
#pragma unroll
    for (int i = 0; i < 4; ++i)
#pragma unroll
      for (int q = 0; q < 4; ++q) {
        int row = m0 + wr * 64 + i * 16 + (lane >> 4) * 4 + q;
        p_att[(size_t)row * HH + col] = f2bf(acc[i][j][q] + bias);
      }
  }
}

// ---------------- per-step device bodies (all HW-validated in R3/R5) ----------------
__device__ __forceinline__ void dev_atth(int nt, const u16* __restrict__ hb, const u16* __restrict__ h2aWb,
                                         const float* __restrict__ h2ab, float* __restrict__ ah) {
  int lane = threadIdx.x & 63;
  int m0 = (threadIdx.x >> 6) * 16, n0 = nt * 16;
  int ak = (lane >> 4) * 8;
  const u16* xr = hb + (size_t)(m0 + (lane & 15)) * HH + ak;
  const u16* wr = h2aWb + (size_t)(n0 + (lane & 15)) * HH + ak;
  f32x4 acc = {0.f, 0.f, 0.f, 0.f};
#pragma unroll
  for (int kk = 0; kk < 16; ++kk)
    acc = mfma16(ldbf(xr + kk * 32), ldbf(wr + kk * 32), acc);
  int col = n0 + (lane & 15);
  float bias = h2ab[col];
#pragma unroll
  for (int j = 0; j < 4; ++j)
    ah[(size_t)(m0 + (lane >> 4) * 4 + j) * HH + col] = acc[j] + bias;
}

__device__ __forceinline__ void dev_e(int bid4, const u16* __restrict__ p_att, const float* __restrict__ ah,
                                      const float* __restrict__ alphaW, const float* __restrict__ alphab,
                                      float* __restrict__ e) {
  int gw = bid4 * 4 + (threadIdx.x >> 6);   // [0, 12544)
  int lane = threadIdx.x & 63;
  int b = gw / LL, l = gw - b * LL;
  short8 pa = ldbf(p_att + (size_t)gw * HH + lane * 8);
  const float4* ap = reinterpret_cast<const float4*>(ah + (size_t)b * HH + lane * 8);
  float4 a0 = ap[0], a1 = ap[1];
  const float4* wp = reinterpret_cast<const float4*>(alphaW + lane * 8);
  float4 w0 = wp[0], w1 = wp[1];
  float s = fast_tanh(bf2f((u16)pa[0]) + a0.x) * w0.x
          + fast_tanh(bf2f((u16)pa[1]) + a0.y) * w0.y
          + fast_tanh(bf2f((u16)pa[2]) + a0.z) * w0.z
          + fast_tanh(bf2f((u16)pa[3]) + a0.w) * w0.w
          + fast_tanh(bf2f((u16)pa[4]) + a1.x) * w1.x
          + fast_tanh(bf2f((u16)pa[5]) + a1.y) * w1.y
          + fast_tanh(bf2f((u16)pa[6]) + a1.z) * w1.z
          + fast_tanh(bf2f((u16)pa[7]) + a1.w) * w1.w;
  s = wred_sum(s);
  if (!lane) e[b * 256 + l] = s + alphab[0];
}

__device__ __forceinline__ void dev_logits(int nt, const u16* __restrict__ hb, const u16* __restrict__ lWb,
                                           const float* __restrict__ lb, float* __restrict__ logits) {
  int lane = threadIdx.x & 63;
  int m0 = (threadIdx.x >> 6) * 16, n0 = nt * 16;
  int ak = (lane >> 4) * 8;
  const u16* xr = hb + (size_t)(m0 + (lane & 15)) * HH + ak;
  int wn = n0 + (lane & 15);
  f32x4 acc = {0.f, 0.f, 0.f, 0.f};
#pragma unroll
  for (int kk = 0; kk < 16; ++kk)
    acc = mfma16(ldbf(xr + kk * 32), ldbf(lWb + (size_t)wn * HH + ak + kk * 32), acc);
  int col = n0 + (lane & 15);
  float bias = lb[col];
#pragma unroll
  for (int j = 0; j < 4; ++j)
    logits[(size_t)(m0 + (lane >> 4) * 4 + j) * VV + col] = acc[j] + bias;
}

__device__ __forceinline__ void dev_lsm(float* red, int b, const float* __restrict__ logits,
                                        float* __restrict__ out, int tstep) {
  const float4* row4 = reinterpret_cast<const float4*>(logits + (size_t)b * VV);
  int t = threadIdx.x, wid = t >> 6, lane = t & 63;
  float4 v[10];
  float m = -1e30f;
#pragma unroll
  for (int p = 0; p < 10; ++p) {
    int i4 = p * 256 + t;
    if (i4 < VV / 4) {
      v[p] = row4[i4];
      m = fmaxf(m, fmaxf(fmaxf(v[p].x, v[p].y), fmaxf(v[p].z, v[p].w)));
    } else {
      v[p] = make_float4(-1e30f, -1e30f, -1e30f, -1e30f);
    }
  }
  m = wred_max(m);
  if (!lane) red[wid] = m;
  __syncthreads();
  m = fmaxf(fmaxf(red[0], red[1]), fmaxf(red[2], red[3]));
  float s = 0.f;
#pragma unroll
  for (int p = 0; p < 10; ++p)
    s += __expf(v[p].x - m) + __expf(v[p].y - m) + __expf(v[p].z - m) + __expf(v[p].w - m);
  s = wred_sum(s);
  if (!lane) red[4 + wid] = s;
  __syncthreads();
  s = red[4] + red[5] + red[6] + red[7];
  float lse = m + __logf(s);
  float4* orow = reinterpret_cast<float4*>(out + ((size_t)b * TT + tstep) * VV);
#pragma unroll
  for (int p = 0; p < 10; ++p) {
    int i4 = p * 256 + t;
    if (i4 < VV / 4)
      orow[i4] = make_float4(v[p].x - lse, v[p].y - lse, v[p].z - lse, v[p].w - lse);
  }
}

// attR: 512 works = b(64) x f-chunk(8) of 256 feats
struct SMattR { float w_s[LL]; float red[8]; float part[4][256]; };
__device__ __forceinline__ void dev_attR2(char* smraw, int w, const float* __restrict__ e,
                                          const u16* __restrict__ attb, u16* __restrict__ xatt) {
  SMattR& s = *reinterpret_cast<SMattR*>(smraw);
  int b = w >> 3, f8 = w & 7;
  int t = threadIdx.x, wid = t >> 6, lane = t & 63;
  float ev = (t < LL) ? e[b * 256 + t] : -1e30f;
  float m = wred_max(ev);
  if (!lane) s.red[wid] = m;
  __syncthreads();
  m = fmaxf(fmaxf(s.red[0], s.red[1]), fmaxf(s.red[2], s.red[3]));
  float ex = __expf(ev - m);
  float sum = wred_sum(ex);
  if (!lane) s.red[4 + wid] = sum;
  __syncthreads();
  sum = s.red[4] + s.red[5] + s.red[6] + s.red[7];
  if (t < LL) s.w_s[t] = ex / sum;
  __syncthreads();

  int f0 = f8 * 256 + lane * 4;
  float a0 = 0.f, a1 = 0.f, a2 = 0.f, a3 = 0.f;
  int l0 = wid * 49;
  const u16* ap = attb + ((size_t)(b * LL + l0)) * FF + f0;
#pragma unroll 7
  for (int l = 0; l < 49; ++l) {
    float wv = s.w_s[l0 + l];
    short4v av = *reinterpret_cast<const short4v*>(ap);
    ap += FF;
    a0 += wv * bf2f((u16)av[0]); a1 += wv * bf2f((u16)av[1]);
    a2 += wv * bf2f((u16)av[2]); a3 += wv * bf2f((u16)av[3]);
  }
  *reinterpret_cast<float4*>(&s.part[wid][lane * 4]) = make_float4(a0, a1, a2, a3);
  __syncthreads();
  float v = s.part[0][t] + s.part[1][t] + s.part[2][t] + s.part[3][t];
  xatt[(size_t)b * FF + f8 * 256 + t] = f2bf(v);
}

// gates+LSTM: 128 works = jt(32) x mq(4); 4 waves = K-quarters
struct SMgl { float sm[4][4][16][16]; };
__device__ __forceinline__ void dev_gatelstm(char* smraw, int work,
                                             const u16* __restrict__ Xemb, const u16* __restrict__ xatt,
                                             const u16* __restrict__ hb_in, const u16* __restrict__ Wc,
                                             float* __restrict__ c, u16* __restrict__ hb_out, int tstep) {
  SMgl& s = *reinterpret_cast<SMgl*>(smraw);
  int jt = work >> 2, mq = work & 3;
  int m0 = mq * 16;
  int lane = threadIdx.x & 63, kq = threadIdx.x >> 6;
  int ar = lane & 15, ak8 = (lane >> 4) * 8;
  int m = m0 + ar;
  int wn = jt * 16 + ar;
  f32x4 zero = {0.f, 0.f, 0.f, 0.f};
  f32x4 acc[4] = {zero, zero, zero, zero};
  const u16* xr0 = Xemb + ((size_t)tstep * BB + m) * HH;
  const u16* xr1 = xatt + (size_t)m * FF;
  const u16* xr2 = hb_in + (size_t)m * HH;

#pragma unroll 4
  for (int kk = 0; kk < 24; ++kk) {
    int k = kq * 768 + kk * 32 + ak8;
    short8 a;
    if (k < 512)       a = ldbf(xr0 + k);
    else if (k < 2560) a = ldbf(xr1 + (k - 512));
    else               a = ldbf(xr2 + (k - 2560));
    short8 bv[4];
#pragma unroll
    for (int g = 0; g < 4; ++g)
      bv[g] = ldbf(Wc + (size_t)(g * 512 + wn) * KXX + k);
#pragma unroll
    for (int g = 0; g < 4; ++g) acc[g] = mfma16(a, bv[g], acc[g]);
  }
#pragma unroll
  for (int g = 0; g < 4; ++g)
#pragma unroll
    for (int q = 0; q < 4; ++q)
      s.sm[kq][g][(lane >> 4) * 4 + q][ar] = acc[g][q];
  __syncthreads();
  int r = threadIdx.x >> 4, cc = threadIdx.x & 15;
  float gi = s.sm[0][0][r][cc] + s.sm[1][0][r][cc] + s.sm[2][0][r][cc] + s.sm[3][0][r][cc];
  float gf = s.sm[0][1][r][cc] + s.sm[1][1][r][cc] + s.sm[2][1][r][cc] + s.sm[3][1][r][cc];
  float gg = s.sm[0][2][r][cc] + s.sm[1][2][r][cc] + s.sm[2][2][r][cc] + s.sm[3][2][r][cc];
  float go = s.sm[0][3][r][cc] + s.sm[1][3][r][cc] + s.sm[2][3][r][cc] + s.sm[3][3][r][cc];
  int idx = (m0 + r) * HH + jt * 16 + cc;
  float cn = fast_sig(gf) * c[idx] + fast_sig(gi) * fast_tanh(gg);
  float hn = fast_sig(go) * fast_tanh(cn);
  c[idx] = cn;
  hb_out[idx] = f2bf(hn);
}

// ---------------- per-step kernels ----------------
__global__ __launch_bounds__(256) void k_atth(const u16* __restrict__ hb, const u16* __restrict__ h2aWb,
                                              const float* __restrict__ h2ab, float* __restrict__ ah) {
  dev_atth(blockIdx.x, hb, h2aWb, h2ab, ah);
}
__global__ __launch_bounds__(256) void k_e(const u16* __restrict__ p_att, const float* __restrict__ ah,
                                           const float* __restrict__ alphaW, const float* __restrict__ alphab,
                                           float* __restrict__ e) {
  dev_e(blockIdx.x, p_att, ah, alphaW, alphab, e);
}
__global__ __launch_bounds__(256) void k_attR(const float* __restrict__ e, const u16* __restrict__ attb,
                                              u16* __restrict__ xatt) {
  __shared__ __align__(16) char smraw[sizeof(SMattR)];
  dev_attR2(smraw, blockIdx.x, e, attb, xatt);
}
__global__ __launch_bounds__(256) void k_gatelstm(const u16* __restrict__ Xemb, const u16* __restrict__ xatt,
                                                  const u16* __restrict__ hb_in, const u16* __restrict__ Wc,
                                                  float* __restrict__ c, u16* __restrict__ hb_out, int tstep) {
  __shared__ __align__(16) char smraw[sizeof(SMgl)];
  dev_gatelstm(smraw, blockIdx.x, Xemb, xatt, hb_in, Wc, c, hb_out, tstep);
}
// logits(t) [0..592]  ∥  atth(t+1) [593..624]
__global__ __launch_bounds__(256) void k_logatt(const u16* __restrict__ hb, const u16* __restrict__ lWb,
                                                const float* __restrict__ lb, float* __restrict__ logits,
                                                const u16* __restrict__ h2aWb, const float* __restrict__ h2ab,
                                                float* __restrict__ ah, int do_next) {
  int bid = blockIdx.x;
  if (bid < 593) dev_logits(bid, hb, lWb, lb, logits);
  else if (do_next) dev_atth(bid - 593, hb, h2aWb, h2ab, ah);
}
// lsm(t) [0..63]  ∥  e(t+1) [64..3199]
__global__ __launch_bounds__(256) void k_lsme(const float* __restrict__ logits, float* __restrict__ out,
                                              int tstep, const u16* __restrict__ p_att,
                                              const float* __restrict__ ah, const float* __restrict__ alphaW,
                                              const float* __restrict__ alphab, float* __restrict__ e,
                                              int do_next) {
  __shared__ float red[8];
  int bid = blockIdx.x;
  if (bid < 64) dev_lsm(red, bid, logits, out, tstep);
  else if (do_next) dev_e(bid - 64, p_att, ah, alphaW, alphab, e);
}

// ---------------- host ----------------
extern "C" void kernel_launch(void* const* d_in, const int* in_sizes, int n_in,
                              void* d_out, int out_size, void* d_ws, size_t ws_size,
                              hipStream_t stream) {
  const float* fc      = (const float*)d_in[0];
  const float* attf    = (const float*)d_in[1];
  const int*   seq     = (const int*)d_in[2];
  const float* lin_W   = (const float*)d_in[3];
  const float* lin_b   = (const float*)d_in[4];
  const float* emb     = (const float*)d_in[5];
  const float* Wih     = (const float*)d_in[6];
  const float* Whh     = (const float*)d_in[7];
  const float* ctx_W   = (const float*)d_in[8];
  const float* ctx_b   = (const float*)d_in[9];
  const float* h2a_W   = (const float*)d_in[10];
  const float* h2a_b   = (const float*)d_in[11];
  const float* alpha_W = (const float*)d_in[12];
  const float* alpha_b = (const float*)d_in[13];
  const float* logit_W = (const float*)d_in[14];
  const float* logit_b = (const float*)d_in[15];
  float* out = (float*)d_out;

  char* base = (char*)d_ws;
  size_t off = 0;
  auto alloc = [&](size_t bytes) -> char* {
    off = (off + 255) & ~(size_t)255;
    char* p = base + off;
    off += bytes;
    return p;
  };
  u16*   p_att  = (u16*)alloc((size_t)MM * HH * 2);
  u16*   ctxWb  = (u16*)alloc((size_t)HH * FF * 2);
  u16*   linWb  = (u16*)alloc((size_t)HH * FF * 2);
  u16*   fcb    = (u16*)alloc((size_t)BB * FF * 2);
  u16*   h2aWb  = (u16*)alloc((size_t)HH * HH * 2);
  u16*   Xemb   = (u16*)alloc((size_t)TT * BB * HH * 2);
  float* c      = (float*)alloc((size_t)BB * HH * 4);
  u16*   hbA    = (u16*)alloc((size_t)BB * HH * 2);
  u16*   hbB    = (u16*)alloc((size_t)BB * HH * 2);
  u16*   xatt   = (u16*)alloc((size_t)BB * FF * 2);
  float* eb     = (float*)alloc((size_t)BB * 256 * 4);
  float* ah     = (float*)alloc((size_t)BB * HH * 4);
  float* logits = (float*)alloc((size_t)BB * VV * 4);
  u16*   Wc     = (u16*)alloc((size_t)2048 * KXX * 2);
  u16*   lWb    = (u16*)alloc((size_t)VV * HH * 2);
  u16*   attb   = (u16*)alloc((size_t)MM * FF * 2);
  (void)ws_size;  // R5 confirmed ws covers this footprint (~110 MB)

  // setup
  k_cvtall<<<7048, 256, 0, stream>>>(ctx_W, ctxWb, lin_W, linWb, h2a_W, h2aWb, logit_W, lWb);
  k_wc<<<(2048 * KXX / 4 + 255) / 256, 256, 0, stream>>>(Wih, Whh, Wc);
  k_cvt<<<(MM * FF / 4 + 255) / 256, 256, 0, stream>>>(attf, attb, MM * FF / 4);
  k_cvt<<<(BB * FF / 4 + 255) / 256, 256, 0, stream>>>(fc, fcb, BB * FF / 4);
  k_xemb<<<(TT * BB * HH / 4 + 255) / 256, 256, 0, stream>>>(emb, seq, Xemb);
  k_h0<<<32, 256, 0, stream>>>(fcb, linWb, lin_b, hbA, c);
  k_patt<<<392, 256, 0, stream>>>(attb, ctxWb, ctx_b, p_att);

  // prologue: ah(0), e(0)
  k_atth<<<32, 256, 0, stream>>>(hbA, h2aWb, h2a_b, ah);
  k_e<<<MM / 4, 256, 0, stream>>>(p_att, ah, alpha_W, alpha_b, eb);

  for (int t = 0; t < TT; ++t) {
    u16* hb_in  = (t & 1) ? hbB : hbA;
    u16* hb_out = (t & 1) ? hbA : hbB;
    int more = (t < TT - 1) ? 1 : 0;
    k_attR<<<512, 256, 0, stream>>>(eb, attb, xatt);
    k_gatelstm<<<128, 256, 0, stream>>>(Xemb, xatt, hb_in, Wc, c, hb_out, t);
    k_logatt<<<625, 256, 0, stream>>>(hb_out, lWb, logit_b, logits, h2aWb, h2a_b, ah, more);
    k_lsme<<<64 + MM / 4, 256, 0, stream>>>(logits, out, t, p_att, ah, alpha_W, alpha_b, eb, more);
  }
}